// Round 12
// baseline (403.822 us; speedup 1.0000x reference)
//
#include <hip/hip_runtime.h>
#include <hip/hip_bf16.h>

#define B_ 4
#define N_ 2048
#define D_ 768
#define H_ 6
#define Do_ 128
#define M_ (B_*N_)      // 8192
#define C2_ (2*D_)      // 1536
#define SROW 49152      // B_*H_*N_

typedef __attribute__((ext_vector_type(8))) short bf16x8;
typedef __attribute__((ext_vector_type(4))) float f32x4;
typedef __attribute__((ext_vector_type(4))) int int4v;
typedef __attribute__((ext_vector_type(2))) int int2v;
typedef __attribute__((ext_vector_type(4))) float float4v;
typedef __attribute__((ext_vector_type(4))) unsigned short ushort4v;

__device__ __forceinline__ float b2f(short s){
    unsigned u = ((unsigned)(unsigned short)s) << 16;
    return __builtin_bit_cast(float, u);
}
__device__ __forceinline__ short f2b(float f){
    unsigned u = __builtin_bit_cast(unsigned, f);
    unsigned r = (u + 0x7fffu + ((u >> 16) & 1u)) >> 16;
    return (short)r;
}
// pack two f32 -> two bf16 (round-half-up) in one v_perm
__device__ __forceinline__ int pk2(float a, float b){
    unsigned ua = __builtin_bit_cast(unsigned, a) + 0x8000u;
    unsigned ub = __builtin_bit_cast(unsigned, b) + 0x8000u;
    return (int)__builtin_amdgcn_perm(ub, ua, 0x07060302u);
}
__device__ __forceinline__ float fast_tanh(float x){
    float a = fabsf(x);
    float e = __expf(-2.0f * a);
    float t = (1.0f - e) / (1.0f + e);
    return copysignf(t, x);
}

// -------- Kernel A: pack B^T matrix (f32->bf16) + bit-pack adj, one launch --------
__global__ __launch_bounds__(256) void k_prep_pack(const float* __restrict__ W,
                                                   const float* __restrict__ Hw,
                                                   const int* __restrict__ adj,
                                                   short* __restrict__ bmat,
                                                   unsigned char* __restrict__ pk){
    int bid = blockIdx.x, t = threadIdx.x;
    if (bid < C2_){
        int c = bid;
        if (c < D_){
            int hd = c >> 7, o = c & 127;
            const float* wp = W + hd*D_*Do_ + o;
            for (int k = t; k < D_; k += 256) bmat[c*D_ + k] = f2b(wp[k*Do_]);
        } else {
            int d = c - D_;
            const float* hp = Hw + d*D_;
            for (int k = t; k < D_; k += 256) bmat[c*D_ + k] = f2b(hp[k]);
        }
    } else {
        int g = (bid - C2_)*256 + t;
        const int* ap = adj + (size_t)g*8;
        int4v a0 = *(const int4v*)ap;
        int4v a1 = *(const int4v*)(ap + 4);
        unsigned by = 0;
        #pragma unroll
        for (int i = 0; i < 4; i++){
            by |= (a0[i] ? 1u : 0u) << i;
            by |= (a1[i] ? 1u : 0u) << (i + 4);
        }
        pk[g] = (unsigned char)by;
    }
}

// -------- Kernel B: C[8192,1536] = A[8192,768] @ Bm^T, 128x128 tile --------
__global__ __launch_bounds__(256) void k_gemm(const float* __restrict__ A,
                                              const short* __restrict__ Bm,
                                              short* __restrict__ ht,
                                              float* outg){
    __shared__ short As[128][72];
    __shared__ short Bs[128][72];
    int tid = threadIdx.x;
    int mBase = blockIdx.y * 128, cBase = blockIdx.x * 128;
    int wave = tid >> 6, lane = tid & 63, q = lane >> 4, nL = lane & 15;
    int wr = (wave >> 1) * 64, wc = (wave & 1) * 64;
    f32x4 acc[4][4] = {};
    for (int kk = 0; kk < D_; kk += 64){
        __syncthreads();
        #pragma unroll
        for (int i = 0; i < 8; i++){
            int idx = tid + i*256;
            int row = idx >> 4, c4 = (idx & 15) * 4;
            float4v av = *(const float4v*)&A[(mBase+row)*D_ + kk + c4];
            int2v w; w[0] = pk2(av[0], av[1]); w[1] = pk2(av[2], av[3]);
            *(int2v*)&As[row][c4] = w;
        }
        #pragma unroll
        for (int i = 0; i < 4; i++){
            int idx = tid + i*256;
            int row = idx >> 3, cs = (idx & 7) * 8;
            *(int4v*)&Bs[row][cs] = *(const int4v*)&Bm[(cBase+row)*D_ + kk + cs];
        }
        __syncthreads();
        #pragma unroll
        for (int k2 = 0; k2 < 64; k2 += 32){
            bf16x8 aF[4], bF[4];
            #pragma unroll
            for (int rt = 0; rt < 4; rt++) aF[rt] = *(const bf16x8*)&As[wr + rt*16 + nL][k2 + q*8];
            #pragma unroll
            for (int ct = 0; ct < 4; ct++) bF[ct] = *(const bf16x8*)&Bs[wc + ct*16 + nL][k2 + q*8];
            #pragma unroll
            for (int rt = 0; rt < 4; rt++)
                #pragma unroll
                for (int ct = 0; ct < 4; ct++)
                    acc[rt][ct] = __builtin_amdgcn_mfma_f32_16x16x32_bf16(aF[rt], bF[ct], acc[rt][ct], 0, 0, 0);
        }
    }
    if (cBase < D_){
        int hd = cBase >> 7;
        #pragma unroll
        for (int rt = 0; rt < 4; rt++){
            #pragma unroll
            for (int ct = 0; ct < 4; ct++){
                int o  = (wc + ct*16 + nL) & 127;
                int m0 = mBase + wr + rt*16 + q*4;
                int b = m0 >> 11, n0 = m0 & 2047;
                ushort4v v;
                #pragma unroll
                for (int r = 0; r < 4; r++) v[r] = (unsigned short)f2b(acc[rt][ct][r]);
                *(ushort4v*)&ht[((b*H_ + hd)*Do_ + o)*N_ + n0] = v;
            }
        }
    } else {
        #pragma unroll
        for (int rt = 0; rt < 4; rt++){
            #pragma unroll
            for (int ct = 0; ct < 4; ct++){
                int d  = cBase - D_ + wc + ct*16 + nL;
                int m0 = mBase + wr + rt*16 + q*4;
                #pragma unroll
                for (int r = 0; r < 4; r++) outg[(size_t)(m0 + r)*D_ + d] = acc[rt][ct][r];
            }
        }
    }
}

// -------- Kernel C: attn_src/dst partials, 4-way o-split --------
__global__ __launch_bounds__(256) void k_stats(const short* __restrict__ ht,
                                               const float* __restrict__ wsrc,
                                               const float* __restrict__ wdst,
                                               float* __restrict__ srcP,
                                               float* __restrict__ dstP){
    int g = blockIdx.x * 256 + threadIdx.x;
    int y = blockIdx.y, o0 = y * 32;
    int bh = g >> 11, n = g & 2047;
    int hd = bh % H_;
    const short* hp = ht + bh*Do_*N_ + n + o0*N_;
    const float* ws = wsrc + hd*Do_ + o0;
    const float* wd = wdst + hd*Do_ + o0;
    float as = 0.f, ad = 0.f;
    for (int o = 0; o < 32; o++){
        float t = fast_tanh(b2f(hp[o*N_]));
        as += t * ws[o];
        ad += t * wd[o];
    }
    srcP[y*SROW + g] = as; dstP[y*SROW + g] = ad;
}

// -------- Kernel E: O = softmax(S)@h fused, kh-split, exp-free, small tiles --------
// Block = 4 waves: wave (rg, kh). 32-row tile (2 row-groups x 16), kh = K-half.
// Each wave: 16 rows x 128 cols over 1024 j's (32 iters, 9 MFMA/iter).
// P = adj ? max(e1_i*E1_j, e2_i*E2_j) : 0 (exp-free); l = P@ones extra MFMA.
// Cross-kh: kh==1 writes acc+accl to LDS, kh==0 adds + epilogues its 16 rows.
// Grid (x=bh 24, y=itile 64): linear = bh + 24*itile, 24%8==0 -> all itiles of
// one bh on one XCD (ht L2-resident). 1536 blocks -> deep wave pool.
struct StageS {
    float E1[2048];             // 8 KB
    float E2[2048];             // 8 KB
    unsigned pkw[32*65];        // 8.32 KB
};
struct RedS { float red[2][64][37]; };  // 18.9 KB, odd stride
union LdsU { StageS s; RedS r; };       // 24.7 KB -> 6 blocks/CU
__global__ __launch_bounds__(256) void k_pv(const unsigned char* __restrict__ pkG,
                                            const float* __restrict__ srcP,
                                            const float* __restrict__ dstP,
                                            const short* __restrict__ ht,
                                            const float* __restrict__ feat_in,
                                            const float* __restrict__ bias,
                                            const float* __restrict__ Hb,
                                            float* outg){
    __shared__ LdsU U;
    int bh = blockIdx.x, itile = blockIdx.y;
    int b = bh / H_, hd = bh % H_;
    int tid = threadIdx.x, wave = tid >> 6, lane = tid & 63, q = lane >> 4, nL = lane & 15;
    int rg = wave >> 1, kh = wave & 1;
    int r0 = itile * 32;
    // ---- stage E1/E2 (sum 4-way dst partials) + packed adj (32 rows) ----
    {
        const float4v* g0 = (const float4v*)(dstP + bh*N_);
        const float4v* g1 = (const float4v*)(dstP + SROW + bh*N_);
        const float4v* g2 = (const float4v*)(dstP + 2*SROW + bh*N_);
        const float4v* g3 = (const float4v*)(dstP + 3*SROW + bh*N_);
        #pragma unroll
        for (int h = 0; h < 2; h++){
            int c4 = tid*2 + h;
            float4v d = g0[c4] + g1[c4] + g2[c4] + g3[c4];
            float4v v1, v2;
            #pragma unroll
            for (int t = 0; t < 4; t++){ v1[t] = __expf(d[t]); v2[t] = __expf(0.2f*d[t]); }
            *(float4v*)&U.s.E1[c4*4] = v1;
            *(float4v*)&U.s.E2[c4*4] = v2;
        }
        const unsigned* pg = (const unsigned*)(pkG + (size_t)(b*N_ + r0) * (N_/8));
        #pragma unroll
        for (int k = 0; k < 8; k++){
            int idx = tid + k*256;              // [0,2048)
            U.s.pkw[(idx >> 6)*65 + (idx & 63)] = pg[idx];
        }
    }
    __syncthreads();
    int rowL = rg*16 + nL;                      // local row in 32-row tile
    int gi = bh*N_ + r0 + rowL;
    float s0 = srcP[gi] + srcP[SROW+gi] + srcP[2*SROW+gi] + srcP[3*SROW+gi];
    float e1r = __expf(s0), e2r = __expf(0.2f*s0);
    bf16x8 vone;
    #pragma unroll
    for (int t = 0; t < 8; t++) vone[t] = (short)0x3F80;
    const short* hp = ht + bh*Do_*N_;
    f32x4 acc[8] = {};
    f32x4 accl = {};
    int base = rowL*65;
    int jEnd = kh*1024 + 1024;
    for (int j0 = kh*1024; j0 < jEnd; j0 += 32){
        unsigned by = (U.s.pkw[base + (j0 >> 5)] >> (q*8)) & 0xFF;
        int kb = j0 + q*8;
        float4v E1a = *(const float4v*)&U.s.E1[kb];
        float4v E1b = *(const float4v*)&U.s.E1[kb + 4];
        float4v E2a = *(const float4v*)&U.s.E2[kb];
        float4v E2b = *(const float4v*)&U.s.E2[kb + 4];
        int4v pi;
        #pragma unroll
        for (int tp = 0; tp < 4; tp++){
            float pa, pb;
            {
                int t = 2*tp;
                float E1t = t < 4 ? E1a[t] : E1b[t-4];
                float E2t = t < 4 ? E2a[t] : E2b[t-4];
                float a = fmaxf(e1r*E1t, e2r*E2t);
                pa = ((by >> t) & 1u) ? a : 0.0f;
            }
            {
                int t = 2*tp + 1;
                float E1t = t < 4 ? E1a[t] : E1b[t-4];
                float E2t = t < 4 ? E2a[t] : E2b[t-4];
                float a = fmaxf(e1r*E1t, e2r*E2t);
                pb = ((by >> t) & 1u) ? a : 0.0f;
            }
            pi[tp] = pk2(pa, pb);
        }
        bf16x8 pf = __builtin_bit_cast(bf16x8, pi);
        #pragma unroll
        for (int ct = 0; ct < 8; ct++){
            bf16x8 bF = *(const bf16x8*)&hp[(ct*16 + nL)*N_ + kb];
            acc[ct] = __builtin_amdgcn_mfma_f32_16x16x32_bf16(pf, bF, acc[ct], 0, 0, 0);
        }
        accl = __builtin_amdgcn_mfma_f32_16x16x32_bf16(pf, vone, accl, 0, 0, 0);
    }
    // ---- cross-kh reduction (one-phase) + epilogue by kh==0 waves ----
    __syncthreads();            // staging dead
    if (kh == 1){
        #pragma unroll
        for (int ct = 0; ct < 8; ct++)
            #pragma unroll
            for (int r = 0; r < 4; r++) U.r.red[rg][lane][ct*4 + r] = acc[ct][r];
        #pragma unroll
        for (int r = 0; r < 4; r++) U.r.red[rg][lane][32 + r] = accl[r];
    }
    __syncthreads();
    if (kh == 0){
        #pragma unroll
        for (int ct = 0; ct < 8; ct++)
            #pragma unroll
            for (int r = 0; r < 4; r++) acc[ct][r] += U.r.red[rg][lane][ct*4 + r];
        #pragma unroll
        for (int r = 0; r < 4; r++) accl[r] += U.r.red[rg][lane][32 + r];
        #pragma unroll
        for (int r = 0; r < 4; r++){
            int i = r0 + rg*16 + q*4 + r;       // C row = q*4+r
            float invl = 1.0f / accl[r];
            size_t obase = (size_t)(b*N_ + i)*D_ + hd*Do_;
            #pragma unroll
            for (int ct = 0; ct < 8; ct++){
                int o = ct*16 + nL;             // C col = lane&15
                float v = acc[ct][r]*invl + bias[o];
                float e = v > 0.f ? v : __expf(v) - 1.0f;
                float gl = outg[obase + o] + Hb[hd*Do_ + o];
                float g = 1.0f / (1.0f + __expf(-gl));
                float fi = feat_in[obase + o];
                outg[obase + o] = g*e + (1.0f - g)*fi;
            }
        }
    }
}

extern "C" void kernel_launch(void* const* d_in, const int* in_sizes, int n_in,
                              void* d_out, int out_size, void* d_ws, size_t ws_size,
                              hipStream_t stream){
    const float* feat = (const float*)d_in[0];
    const int*   adj  = (const int*)  d_in[1];
    const float* W    = (const float*)d_in[2];
    const float* bias = (const float*)d_in[3];
    const float* wsrc = (const float*)d_in[4];
    const float* wdst = (const float*)d_in[5];
    const float* Hw   = (const float*)d_in[6];
    const float* Hb   = (const float*)d_in[7];
    float* out = (float*)d_out;
    char* ws = (char*)d_ws;
    short* bmat = (short*)(ws);
    short* ht   = (short*)(ws + 2359296);
    float* srcP = (float*)(ws + 14942208);
    float* dstP = (float*)(ws + 15728640);
    unsigned char* pk = (unsigned char*)(ws + 16515072);

    hipLaunchKernelGGL(k_prep_pack, dim3(C2_ + 8192), dim3(256), 0, stream, W, Hw, adj, bmat, pk);
    hipLaunchKernelGGL(k_gemm,      dim3(12, 64),     dim3(256), 0, stream, feat, bmat, ht, out);
    hipLaunchKernelGGL(k_stats,     dim3(192, 4),     dim3(256), 0, stream, ht, wsrc, wdst, srcP, dstP);
    hipLaunchKernelGGL(k_pv,        dim3(24, 64),     dim3(256), 0, stream, pk, srcP, dstP,
                       ht, feat, bias, Hb, out);
}

// Round 13
// 324.433 us; speedup vs baseline: 1.2447x; 1.2447x over previous
//
#include <hip/hip_runtime.h>
#include <hip/hip_bf16.h>

#define B_ 4
#define N_ 2048
#define D_ 768
#define H_ 6
#define Do_ 128
#define M_ (B_*N_)      // 8192
#define C2_ (2*D_)      // 1536
#define SROW 49152      // B_*H_*N_

typedef __attribute__((ext_vector_type(8))) short bf16x8;
typedef __attribute__((ext_vector_type(4))) float f32x4;
typedef __attribute__((ext_vector_type(4))) int int4v;
typedef __attribute__((ext_vector_type(2))) int int2v;
typedef __attribute__((ext_vector_type(4))) float float4v;
typedef __attribute__((ext_vector_type(4))) unsigned short ushort4v;

__device__ __forceinline__ float b2f(short s){
    unsigned u = ((unsigned)(unsigned short)s) << 16;
    return __builtin_bit_cast(float, u);
}
__device__ __forceinline__ short f2b(float f){
    unsigned u = __builtin_bit_cast(unsigned, f);
    unsigned r = (u + 0x7fffu + ((u >> 16) & 1u)) >> 16;
    return (short)r;
}
// pack two f32 -> two bf16 (round-half-up) in one v_perm
__device__ __forceinline__ int pk2(float a, float b){
    unsigned ua = __builtin_bit_cast(unsigned, a) + 0x8000u;
    unsigned ub = __builtin_bit_cast(unsigned, b) + 0x8000u;
    return (int)__builtin_amdgcn_perm(ub, ua, 0x07060302u);
}
__device__ __forceinline__ float fast_tanh(float x){
    float a = fabsf(x);
    float e = __expf(-2.0f * a);
    float t = (1.0f - e) / (1.0f + e);
    return copysignf(t, x);
}

// -------- Kernel A: pack B^T matrix (f32->bf16) + bit-pack adj, one launch --------
__global__ __launch_bounds__(256) void k_prep_pack(const float* __restrict__ W,
                                                   const float* __restrict__ Hw,
                                                   const int* __restrict__ adj,
                                                   short* __restrict__ bmat,
                                                   unsigned char* __restrict__ pk){
    int bid = blockIdx.x, t = threadIdx.x;
    if (bid < C2_){
        int c = bid;
        if (c < D_){
            int hd = c >> 7, o = c & 127;
            const float* wp = W + hd*D_*Do_ + o;
            for (int k = t; k < D_; k += 256) bmat[c*D_ + k] = f2b(wp[k*Do_]);
        } else {
            int d = c - D_;
            const float* hp = Hw + d*D_;
            for (int k = t; k < D_; k += 256) bmat[c*D_ + k] = f2b(hp[k]);
        }
    } else {
        int g = (bid - C2_)*256 + t;
        const int* ap = adj + (size_t)g*8;
        int4v a0 = *(const int4v*)ap;
        int4v a1 = *(const int4v*)(ap + 4);
        unsigned by = 0;
        #pragma unroll
        for (int i = 0; i < 4; i++){
            by |= (a0[i] ? 1u : 0u) << i;
            by |= (a1[i] ? 1u : 0u) << (i + 4);
        }
        pk[g] = (unsigned char)by;
    }
}

// -------- Kernel B: C[8192,1536] = A[8192,768] @ Bm^T, 128x128 tile --------
__global__ __launch_bounds__(256) void k_gemm(const float* __restrict__ A,
                                              const short* __restrict__ Bm,
                                              short* __restrict__ ht,
                                              float* outg){
    __shared__ short As[128][72];
    __shared__ short Bs[128][72];
    int tid = threadIdx.x;
    int mBase = blockIdx.y * 128, cBase = blockIdx.x * 128;
    int wave = tid >> 6, lane = tid & 63, q = lane >> 4, nL = lane & 15;
    int wr = (wave >> 1) * 64, wc = (wave & 1) * 64;
    f32x4 acc[4][4] = {};
    for (int kk = 0; kk < D_; kk += 64){
        __syncthreads();
        #pragma unroll
        for (int i = 0; i < 8; i++){
            int idx = tid + i*256;
            int row = idx >> 4, c4 = (idx & 15) * 4;
            float4v av = *(const float4v*)&A[(mBase+row)*D_ + kk + c4];
            int2v w; w[0] = pk2(av[0], av[1]); w[1] = pk2(av[2], av[3]);
            *(int2v*)&As[row][c4] = w;
        }
        #pragma unroll
        for (int i = 0; i < 4; i++){
            int idx = tid + i*256;
            int row = idx >> 3, cs = (idx & 7) * 8;
            *(int4v*)&Bs[row][cs] = *(const int4v*)&Bm[(cBase+row)*D_ + kk + cs];
        }
        __syncthreads();
        #pragma unroll
        for (int k2 = 0; k2 < 64; k2 += 32){
            bf16x8 aF[4], bF[4];
            #pragma unroll
            for (int rt = 0; rt < 4; rt++) aF[rt] = *(const bf16x8*)&As[wr + rt*16 + nL][k2 + q*8];
            #pragma unroll
            for (int ct = 0; ct < 4; ct++) bF[ct] = *(const bf16x8*)&Bs[wc + ct*16 + nL][k2 + q*8];
            #pragma unroll
            for (int rt = 0; rt < 4; rt++)
                #pragma unroll
                for (int ct = 0; ct < 4; ct++)
                    acc[rt][ct] = __builtin_amdgcn_mfma_f32_16x16x32_bf16(aF[rt], bF[ct], acc[rt][ct], 0, 0, 0);
        }
    }
    if (cBase < D_){
        int hd = cBase >> 7;
        #pragma unroll
        for (int rt = 0; rt < 4; rt++){
            #pragma unroll
            for (int ct = 0; ct < 4; ct++){
                int o  = (wc + ct*16 + nL) & 127;
                int m0 = mBase + wr + rt*16 + q*4;
                int b = m0 >> 11, n0 = m0 & 2047;
                ushort4v v;
                #pragma unroll
                for (int r = 0; r < 4; r++) v[r] = (unsigned short)f2b(acc[rt][ct][r]);
                *(ushort4v*)&ht[((b*H_ + hd)*Do_ + o)*N_ + n0] = v;
            }
        }
    } else {
        #pragma unroll
        for (int rt = 0; rt < 4; rt++){
            #pragma unroll
            for (int ct = 0; ct < 4; ct++){
                int d  = cBase - D_ + wc + ct*16 + nL;
                int m0 = mBase + wr + rt*16 + q*4;
                #pragma unroll
                for (int r = 0; r < 4; r++) outg[(size_t)(m0 + r)*D_ + d] = acc[rt][ct][r];
            }
        }
    }
}

// -------- Kernel C: attn_src/dst partials, 4-way o-split --------
__global__ __launch_bounds__(256) void k_stats(const short* __restrict__ ht,
                                               const float* __restrict__ wsrc,
                                               const float* __restrict__ wdst,
                                               float* __restrict__ srcP,
                                               float* __restrict__ dstP){
    int g = blockIdx.x * 256 + threadIdx.x;
    int y = blockIdx.y, o0 = y * 32;
    int bh = g >> 11, n = g & 2047;
    int hd = bh % H_;
    const short* hp = ht + bh*Do_*N_ + n + o0*N_;
    const float* ws = wsrc + hd*Do_ + o0;
    const float* wd = wdst + hd*Do_ + o0;
    float as = 0.f, ad = 0.f;
    for (int o = 0; o < 32; o++){
        float t = fast_tanh(b2f(hp[o*N_]));
        as += t * ws[o];
        ad += t * wd[o];
    }
    srcP[y*SROW + g] = as; dstP[y*SROW + g] = ad;
}

// -------- Kernel E: O = softmax(S)@h, R8 2-frag kh-split + exp-free P --------
// Block = 4 waves: wave (rh, kh); rh = row-half (32 rows via 2 A-frags), kh =
// K-half. Both frags share bF loads (18 MFMA per 8 loads — R8's ratio, the
// measured-fastest shape) and the E1/E2 LDS reads. P = adj ? max(e1_i*E1_j,
// e2_i*E2_j) : 0 (exp-free). l = P@ones via ones-MFMA (C rows q*4+r match
// epilogue). One-phase reduction (R8-proven, no spill), stride-73 red.
// Grid (x=bh 24, y=itile 32): 24%8==0 -> all itiles of one bh on one XCD.
struct StageS {
    float E1[2048];             // 8 KB
    float E2[2048];             // 8 KB
    unsigned pkw[64*65];        // 16.64 KB
};
struct RedS { float red[2][64][73]; };  // 37.4 KB; [rh][lane][f*32+ct*4+r | 64+f*4+r]
union LdsU { StageS s; RedS r; };
__global__ __launch_bounds__(256) void k_pv(const unsigned char* __restrict__ pkG,
                                            const float* __restrict__ srcP,
                                            const float* __restrict__ dstP,
                                            const short* __restrict__ ht,
                                            const float* __restrict__ feat_in,
                                            const float* __restrict__ bias,
                                            const float* __restrict__ Hb,
                                            float* outg){
    __shared__ LdsU U;
    int bh = blockIdx.x, itile = blockIdx.y;
    int b = bh / H_, hd = bh % H_;
    int tid = threadIdx.x, wave = tid >> 6, lane = tid & 63, q = lane >> 4, nL = lane & 15;
    int rh = wave >> 1, kh = wave & 1;
    int r0 = itile * 64;
    // ---- stage E1/E2 (sum 4-way dst partials) + packed adj (64 rows) ----
    {
        const float4v* g0 = (const float4v*)(dstP + bh*N_);
        const float4v* g1 = (const float4v*)(dstP + SROW + bh*N_);
        const float4v* g2 = (const float4v*)(dstP + 2*SROW + bh*N_);
        const float4v* g3 = (const float4v*)(dstP + 3*SROW + bh*N_);
        #pragma unroll
        for (int h = 0; h < 2; h++){
            int c4 = tid*2 + h;
            float4v d = g0[c4] + g1[c4] + g2[c4] + g3[c4];
            float4v v1, v2;
            #pragma unroll
            for (int t = 0; t < 4; t++){ v1[t] = __expf(d[t]); v2[t] = __expf(0.2f*d[t]); }
            *(float4v*)&U.s.E1[c4*4] = v1;
            *(float4v*)&U.s.E2[c4*4] = v2;
        }
        const unsigned* pg = (const unsigned*)(pkG + (size_t)(b*N_ + r0) * (N_/8));
        #pragma unroll
        for (int k = 0; k < 16; k++){
            int idx = tid + k*256;              // [0,4096)
            U.s.pkw[(idx >> 6)*65 + (idx & 63)] = pg[idx];
        }
    }
    __syncthreads();
    int rowL0 = rh*32 + nL, rowL1 = rowL0 + 16;
    int gi0 = bh*N_ + r0 + rowL0, gi1 = bh*N_ + r0 + rowL1;
    float s0 = srcP[gi0] + srcP[SROW+gi0] + srcP[2*SROW+gi0] + srcP[3*SROW+gi0];
    float s1 = srcP[gi1] + srcP[SROW+gi1] + srcP[2*SROW+gi1] + srcP[3*SROW+gi1];
    float e1r0 = __expf(s0), e2r0 = __expf(0.2f*s0);
    float e1r1 = __expf(s1), e2r1 = __expf(0.2f*s1);
    bf16x8 vone;
    #pragma unroll
    for (int t = 0; t < 8; t++) vone[t] = (short)0x3F80;
    const short* hp = ht + bh*Do_*N_;
    f32x4 acc[2][8] = {};
    f32x4 accl0 = {}, accl1 = {};
    int base0 = rowL0*65, base1 = rowL1*65;
    int jEnd = kh*1024 + 1024;
    for (int j0 = kh*1024; j0 < jEnd; j0 += 32){
        unsigned by0 = (U.s.pkw[base0 + (j0 >> 5)] >> (q*8)) & 0xFF;
        unsigned by1 = (U.s.pkw[base1 + (j0 >> 5)] >> (q*8)) & 0xFF;
        int kb = j0 + q*8;
        float4v E1a = *(const float4v*)&U.s.E1[kb];
        float4v E1b = *(const float4v*)&U.s.E1[kb + 4];
        float4v E2a = *(const float4v*)&U.s.E2[kb];
        float4v E2b = *(const float4v*)&U.s.E2[kb + 4];
        int4v pi0, pi1;
        #pragma unroll
        for (int tp = 0; tp < 4; tp++){
            float pa0, pb0, pa1, pb1;
            {
                int t = 2*tp;
                float E1t = t < 4 ? E1a[t] : E1b[t-4];
                float E2t = t < 4 ? E2a[t] : E2b[t-4];
                float a0 = fmaxf(e1r0*E1t, e2r0*E2t);
                float a1 = fmaxf(e1r1*E1t, e2r1*E2t);
                pa0 = ((by0 >> t) & 1u) ? a0 : 0.0f;
                pa1 = ((by1 >> t) & 1u) ? a1 : 0.0f;
            }
            {
                int t = 2*tp + 1;
                float E1t = t < 4 ? E1a[t] : E1b[t-4];
                float E2t = t < 4 ? E2a[t] : E2b[t-4];
                float a0 = fmaxf(e1r0*E1t, e2r0*E2t);
                float a1 = fmaxf(e1r1*E1t, e2r1*E2t);
                pb0 = ((by0 >> t) & 1u) ? a0 : 0.0f;
                pb1 = ((by1 >> t) & 1u) ? a1 : 0.0f;
            }
            pi0[tp] = pk2(pa0, pb0);
            pi1[tp] = pk2(pa1, pb1);
        }
        bf16x8 pf0 = __builtin_bit_cast(bf16x8, pi0);
        bf16x8 pf1 = __builtin_bit_cast(bf16x8, pi1);
        #pragma unroll
        for (int ct = 0; ct < 8; ct++){
            bf16x8 bF = *(const bf16x8*)&hp[(ct*16 + nL)*N_ + kb];
            acc[0][ct] = __builtin_amdgcn_mfma_f32_16x16x32_bf16(pf0, bF, acc[0][ct], 0, 0, 0);
            acc[1][ct] = __builtin_amdgcn_mfma_f32_16x16x32_bf16(pf1, bF, acc[1][ct], 0, 0, 0);
        }
        accl0 = __builtin_amdgcn_mfma_f32_16x16x32_bf16(pf0, vone, accl0, 0, 0, 0);
        accl1 = __builtin_amdgcn_mfma_f32_16x16x32_bf16(pf1, vone, accl1, 0, 0, 0);
    }
    // ---- one-phase cross-kh reduction (R8 structure) ----
    __syncthreads();            // staging dead
    if (kh == 1){
        #pragma unroll
        for (int f = 0; f < 2; f++)
            #pragma unroll
            for (int ct = 0; ct < 8; ct++)
                #pragma unroll
                for (int r = 0; r < 4; r++)
                    U.r.red[rh][lane][f*32 + ct*4 + r] = f ? acc[1][ct][r] : acc[0][ct][r];
        #pragma unroll
        for (int r = 0; r < 4; r++){
            U.r.red[rh][lane][64 + r] = accl0[r];
            U.r.red[rh][lane][68 + r] = accl1[r];
        }
    }
    __syncthreads();
    if (kh == 0){
        #pragma unroll
        for (int f = 0; f < 2; f++)
            #pragma unroll
            for (int ct = 0; ct < 8; ct++)
                #pragma unroll
                for (int r = 0; r < 4; r++)
                    acc[f][ct][r] += U.r.red[rh][lane][f*32 + ct*4 + r];
        #pragma unroll
        for (int r = 0; r < 4; r++){
            accl0[r] += U.r.red[rh][lane][64 + r];
            accl1[r] += U.r.red[rh][lane][68 + r];
        }
        #pragma unroll
        for (int f = 0; f < 2; f++){
            #pragma unroll
            for (int r = 0; r < 4; r++){
                int i = r0 + rh*32 + f*16 + q*4 + r;    // C row = q*4+r
                float invl = 1.0f / (f ? accl1[r] : accl0[r]);
                size_t obase = (size_t)(b*N_ + i)*D_ + hd*Do_;
                #pragma unroll
                for (int ct = 0; ct < 8; ct++){
                    int o = ct*16 + nL;                 // C col = lane&15
                    float v = acc[f][ct][r]*invl + bias[o];
                    float e = v > 0.f ? v : __expf(v) - 1.0f;
                    float gl = outg[obase + o] + Hb[hd*Do_ + o];
                    float g = 1.0f / (1.0f + __expf(-gl));
                    float fi = feat_in[obase + o];
                    outg[obase + o] = g*e + (1.0f - g)*fi;
                }
            }
        }
    }
}

extern "C" void kernel_launch(void* const* d_in, const int* in_sizes, int n_in,
                              void* d_out, int out_size, void* d_ws, size_t ws_size,
                              hipStream_t stream){
    const float* feat = (const float*)d_in[0];
    const int*   adj  = (const int*)  d_in[1];
    const float* W    = (const float*)d_in[2];
    const float* bias = (const float*)d_in[3];
    const float* wsrc = (const float*)d_in[4];
    const float* wdst = (const float*)d_in[5];
    const float* Hw   = (const float*)d_in[6];
    const float* Hb   = (const float*)d_in[7];
    float* out = (float*)d_out;
    char* ws = (char*)d_ws;
    short* bmat = (short*)(ws);
    short* ht   = (short*)(ws + 2359296);
    float* srcP = (float*)(ws + 14942208);
    float* dstP = (float*)(ws + 15728640);
    unsigned char* pk = (unsigned char*)(ws + 16515072);

    hipLaunchKernelGGL(k_prep_pack, dim3(C2_ + 8192), dim3(256), 0, stream, W, Hw, adj, bmat, pk);
    hipLaunchKernelGGL(k_gemm,      dim3(12, 64),     dim3(256), 0, stream, feat, bmat, ht, out);
    hipLaunchKernelGGL(k_stats,     dim3(192, 4),     dim3(256), 0, stream, ht, wsrc, wdst, srcP, dstP);
    hipLaunchKernelGGL(k_pv,        dim3(24, 32),     dim3(256), 0, stream, pk, srcP, dstP,
                       ht, feat, bias, Hb, out);
}